// Round 1
// baseline (1110.422 us; speedup 1.0000x reference)
//
#include <hip/hip_runtime.h>
#include <math.h>

#define N_NODES 100000
#define N_EDGES 6400000
#define NF 128
#define NH 16
#define SCAN_BLK 196   // 196*512 = 100352 >= 100000

// ---------------- histogram of dst (in-degree, no self loop yet) ----------------
__global__ __launch_bounds__(256) void k_hist(const int* __restrict__ dst, int* __restrict__ deg) {
    int i = blockIdx.x * 256 + threadIdx.x;
    if (i < N_EDGES) atomicAdd(&deg[dst[i]], 1);
}

// ---------------- scan phase A: per-block sums of deg ----------------
__global__ __launch_bounds__(512) void k_scan_a(const int* __restrict__ deg, int* __restrict__ partial) {
    __shared__ int lds[8];
    int i = blockIdx.x * 512 + threadIdx.x;
    int v = (i < N_NODES) ? deg[i] : 0;
    #pragma unroll
    for (int d = 1; d < 64; d <<= 1) v += __shfl_xor(v, d, 64);
    int wave = threadIdx.x >> 6;
    if ((threadIdx.x & 63) == 0) lds[wave] = v;
    __syncthreads();
    if (threadIdx.x == 0) {
        int s = 0;
        #pragma unroll
        for (int w = 0; w < 8; w++) s += lds[w];
        partial[blockIdx.x] = s;
    }
}

// ---------------- scan phase B: exclusive scan of block partials (single block) ----------------
__global__ __launch_bounds__(256) void k_scan_b(int* __restrict__ partial, int* __restrict__ off) {
    __shared__ int lds[256];
    int t = threadIdx.x;
    int v = (t < SCAN_BLK) ? partial[t] : 0;
    lds[t] = v;
    __syncthreads();
    for (int d = 1; d < 256; d <<= 1) {
        int add = (t >= d) ? lds[t - d] : 0;
        __syncthreads();
        lds[t] += add;
        __syncthreads();
    }
    if (t < SCAN_BLK) partial[t] = lds[t] - v;      // exclusive
    if (t == SCAN_BLK - 1) off[N_NODES] = lds[t];   // total edge count
}

// ---------------- scan phase C: block-level exclusive scan -> off/cur, plus dinv ----------------
__global__ __launch_bounds__(512) void k_scan_c(const int* __restrict__ deg, const int* __restrict__ partial,
                                                int* __restrict__ off, int* __restrict__ cur,
                                                float* __restrict__ dinv) {
    __shared__ int wsum[8];
    int t = threadIdx.x;
    int i = blockIdx.x * 512 + t;
    int v = (i < N_NODES) ? deg[i] : 0;
    int lane = t & 63, wave = t >> 6;
    int inc = v;
    #pragma unroll
    for (int d = 1; d < 64; d <<= 1) {
        int u = __shfl_up(inc, d, 64);
        if (lane >= d) inc += u;
    }
    if (lane == 63) wsum[wave] = inc;
    __syncthreads();
    int woff = 0;
    for (int w = 0; w < wave; w++) woff += wsum[w];
    int exc = inc - v + woff + partial[blockIdx.x];
    if (i < N_NODES) {
        off[i] = exc;
        cur[i] = exc;
        dinv[i] = rsqrtf((float)(v + 1));  // +1 self loop
    }
}

// ---------------- scatter edges into dst-sorted buckets ----------------
__global__ __launch_bounds__(256) void k_scatter(const int* __restrict__ src, const int* __restrict__ dst,
                                                 int* __restrict__ cur, int* __restrict__ sorted) {
    int i = blockIdx.x * 256 + threadIdx.x;
    if (i < N_EDGES) {
        int d = dst[i];
        int p = atomicAdd(&cur[d], 1);
        sorted[p] = src[i];
    }
}

// ---------------- g1 = dinv * (x @ W1) ----------------
__global__ __launch_bounds__(256) void k_gemm1(const float* __restrict__ x, const float* __restrict__ W1,
                                               const float* __restrict__ dinv, float* __restrict__ g1) {
    __shared__ float Ws[NF * NH];  // 8 KB
    for (int i = threadIdx.x; i < NF * NH; i += 256) Ws[i] = W1[i];
    __syncthreads();
    int gid = blockIdx.x * 256 + threadIdx.x;
    int n = gid >> 4, j = gid & 15;
    if (n >= N_NODES) return;
    const float4* xr = (const float4*)(x + (size_t)n * NF);
    float acc = 0.f;
    #pragma unroll
    for (int k4 = 0; k4 < NF / 4; k4++) {
        float4 v = xr[k4];
        acc += v.x * Ws[(k4 * 4 + 0) * NH + j];
        acc += v.y * Ws[(k4 * 4 + 1) * NH + j];
        acc += v.z * Ws[(k4 * 4 + 2) * NH + j];
        acc += v.w * Ws[(k4 * 4 + 3) * NH + j];
    }
    g1[n * NH + j] = dinv[n] * acc;
}

// ---------------- pull-mode aggregate; LAYER1: fused relu+W2, LAYER2: sigmoid out ----------------
template <int LAYER>
__global__ __launch_bounds__(256) void k_agg(const float* __restrict__ g, const int* __restrict__ off,
                                             const int* __restrict__ sorted, const float* __restrict__ dinv,
                                             const float* __restrict__ bias, const float* __restrict__ W2,
                                             float* __restrict__ outp) {
    __shared__ float W2s[NH * NH];
    if (LAYER == 1) {
        for (int i = threadIdx.x; i < NH * NH; i += 256) W2s[i] = W2[i];
        __syncthreads();
    }
    int n = blockIdx.x * 4 + (threadIdx.x >> 6);  // 1 node per wave
    if (n >= N_NODES) return;
    int lane = threadIdx.x & 63;
    int q = lane >> 4, j = lane & 15;
    int o0 = off[n], o1 = off[n + 1];
    float acc = (q == 0) ? g[n * NH + j] : 0.f;  // self-loop term (g already dinv-scaled)
    for (int e = o0 + q; e < o1; e += 4) {
        int s = sorted[e];
        acc += g[s * NH + j];
    }
    acc += __shfl_xor(acc, 16, 64);
    acc += __shfl_xor(acc, 32, 64);
    float dn = dinv[n];
    if (LAYER == 1) {
        float r = fmaxf(dn * acc + bias[j], 0.f);
        float h2 = 0.f;
        #pragma unroll
        for (int k = 0; k < NH; k++) h2 += __shfl(r, k, 64) * W2s[k * NH + j];
        if (q == 0) outp[n * NH + j] = dn * h2;
    } else {
        if (q == 0) {
            float z = dn * acc + bias[j];
            outp[n * NH + j] = 1.f / (1.f + __expf(-z));
        }
    }
}

extern "C" void kernel_launch(void* const* d_in, const int* in_sizes, int n_in,
                              void* d_out, int out_size, void* d_ws, size_t ws_size,
                              hipStream_t stream) {
    const float* x   = (const float*)d_in[0];
    const int* eidx  = (const int*)d_in[1];
    const float* W1  = (const float*)d_in[2];
    const float* b1  = (const float*)d_in[3];
    const float* W2  = (const float*)d_in[4];
    const float* b2  = (const float*)d_in[5];
    const int* src = eidx;
    const int* dst = eidx + N_EDGES;
    float* out = (float*)d_out;

    // workspace layout (256B aligned)
    char* ws = (char*)d_ws;
    size_t o = 0;
    auto alloc = [&](size_t bytes) { size_t r = o; o = (o + bytes + 255) & ~(size_t)255; return r; };
    int*   deg    = (int*)  (ws + alloc(sizeof(int) * N_NODES));
    int*   off    = (int*)  (ws + alloc(sizeof(int) * (N_NODES + 1)));
    int*   cur    = (int*)  (ws + alloc(sizeof(int) * N_NODES));
    float* dinv   = (float*)(ws + alloc(sizeof(float) * N_NODES));
    int*   part   = (int*)  (ws + alloc(sizeof(int) * 256));
    int*   sorted = (int*)  (ws + alloc(sizeof(int) * N_EDGES));
    float* g1     = (float*)(ws + alloc(sizeof(float) * N_NODES * NH));
    float* g2     = (float*)(ws + alloc(sizeof(float) * N_NODES * NH));
    (void)ws_size; (void)n_in; (void)in_sizes; (void)out_size;

    hipMemsetAsync(deg, 0, sizeof(int) * N_NODES, stream);

    // CSR build
    k_hist<<<(N_EDGES + 255) / 256, 256, 0, stream>>>(dst, deg);
    k_scan_a<<<SCAN_BLK, 512, 0, stream>>>(deg, part);
    k_scan_b<<<1, 256, 0, stream>>>(part, off);
    k_scan_c<<<SCAN_BLK, 512, 0, stream>>>(deg, part, off, cur, dinv);
    k_scatter<<<(N_EDGES + 255) / 256, 256, 0, stream>>>(src, dst, cur, sorted);

    // layer 1 dense transform (dinv-folded)
    k_gemm1<<<(N_NODES * NH + 255) / 256, 256, 0, stream>>>(x, W1, dinv, g1);

    // layer 1 aggregate + relu + W2 (dinv-folded into g2)
    k_agg<1><<<(N_NODES + 3) / 4, 256, 0, stream>>>(g1, off, sorted, dinv, b1, W2, g2);

    // layer 2 aggregate + bias + sigmoid
    k_agg<2><<<(N_NODES + 3) / 4, 256, 0, stream>>>(g2, off, sorted, dinv, b2, nullptr, out);
}